// Round 32
// baseline (78.341 us; speedup 1.0000x reference)
//
#include <hip/hip_runtime.h>
#include <hip/hip_bf16.h>

#define CC 1024
#define NN 1024
#define BB 2
#define HH 16
#define NT (NN / 64)
#define QSCALE 0.17677669529663687f  // 1/sqrt(32)

typedef short bf16x8 __attribute__((ext_vector_type(8)));
typedef float f32x4  __attribute__((ext_vector_type(4)));
typedef unsigned int u32x2 __attribute__((ext_vector_type(2)));

__device__ __forceinline__ f32x4 mfma16(bf16x8 a, bf16x8 b, f32x4 c) {
    return __builtin_amdgcn_mfma_f32_16x16x32_bf16(a, b, c, 0, 0, 0);
}
__device__ __forceinline__ short f2bf(float x) {
    __hip_bfloat16 h = __float2bfloat16(x);
    return *reinterpret_cast<short*>(&h);
}
__device__ __forceinline__ float bf2f(short s) {
    __hip_bfloat16 h;
    *reinterpret_cast<short*>(&h) = s;
    return __bfloat162float(h);
}
// XCD-chunked swizzle (bijective when nwg % 8 == 0).
__device__ __forceinline__ int xcd_logical(int hw, int nwg) {
    return (hw & 7) * (nwg >> 3) + (hw >> 3);
}

// ---------------------------------------------------------------------------
// Fused QKV projection (champion): tile 128x64, BK=64, 512 thr / 8 waves,
// per-wave 32x32, grid 768 (XCD-chunked), 6 waves/SIMD.
// ---------------------------------------------------------------------------
__global__ __launch_bounds__(512) void qkv_proj(
    const float* __restrict__ xq, const float* __restrict__ xk, const float* __restrict__ xv,
    const float* __restrict__ wq, const float* __restrict__ wk, const float* __restrict__ wv,
    const float* __restrict__ bq, const float* __restrict__ bk, const float* __restrict__ bv,
    short* __restrict__ qt, short* __restrict__ kt, short* __restrict__ vt)
{
    __shared__ short LD[13824];                        // 27,648 B
    short (*A)[72]  = (short(*)[72])LD;                // 128 x 72
    short (*Bt)[72] = (short(*)[72])(LD + 128 * 72);   // 64 x 72
    short (*T)[136] = (short(*)[136])LD;               // z=2 overlay: 64 x 136

    const int L = xcd_logical(blockIdx.x, 768);
    const int z = L >> 8;                 // /256
    const int rem = L & 255;
    const int row0 = (rem >> 4) * 128;    // 16 row-blocks
    const int col0 = (rem & 15) * 64;     // 16 col-blocks

    const int tid  = threadIdx.x;
    const int lane = tid & 63, wid = tid >> 6;     // 8 waves
    const int wr = wid >> 1, wc = wid & 1;         // 4 x 2: per-wave 32 x 32
    const int l16 = lane & 15, lk = lane >> 4;

    const float* X    = (z == 0) ? xq : (z == 1) ? xk : xv;
    const float* W    = (z == 0) ? wq : (z == 1) ? wk : wv;
    const float* bias = (z == 0) ? bq : (z == 1) ? bk : bv;

    const int str = tid >> 4;          // 0..31
    const int stc = (tid & 15) << 2;   // 0..60

    float4 pa[4], pb[2];
#pragma unroll
    for (int p = 0; p < 4; ++p)
        pa[p] = *(const float4*)&X[(size_t)(row0 + p * 32 + str) * CC + stc];
#pragma unroll
    for (int p = 0; p < 2; ++p)
        pb[p] = *(const float4*)&W[(size_t)(col0 + p * 32 + str) * CC + stc];

    f32x4 acc[2][2];
#pragma unroll
    for (int i = 0; i < 2; ++i)
#pragma unroll
        for (int j = 0; j < 2; ++j) acc[i][j] = (f32x4){0.f, 0.f, 0.f, 0.f};

    for (int k0 = 0; k0 < CC; k0 += 64) {
#pragma unroll
        for (int p = 0; p < 4; ++p) {
            ushort4 ua = { (unsigned short)f2bf(pa[p].x), (unsigned short)f2bf(pa[p].y),
                           (unsigned short)f2bf(pa[p].z), (unsigned short)f2bf(pa[p].w) };
            *(ushort4*)&A[p * 32 + str][stc] = ua;
        }
#pragma unroll
        for (int p = 0; p < 2; ++p) {
            ushort4 ub = { (unsigned short)f2bf(pb[p].x), (unsigned short)f2bf(pb[p].y),
                           (unsigned short)f2bf(pb[p].z), (unsigned short)f2bf(pb[p].w) };
            *(ushort4*)&Bt[p * 32 + str][stc] = ub;
        }
        if (k0 + 64 < CC) {
#pragma unroll
            for (int p = 0; p < 4; ++p)
                pa[p] = *(const float4*)&X[(size_t)(row0 + p * 32 + str) * CC + k0 + 64 + stc];
#pragma unroll
            for (int p = 0; p < 2; ++p)
                pb[p] = *(const float4*)&W[(size_t)(col0 + p * 32 + str) * CC + k0 + 64 + stc];
        }
        __syncthreads();
#pragma unroll
        for (int ks = 0; ks < 2; ++ks) {
            bf16x8 af[2], bw[2];
#pragma unroll
            for (int i = 0; i < 2; ++i)
                af[i] = *(const bf16x8*)&A[wr * 32 + i * 16 + l16][ks * 32 + lk * 8];
#pragma unroll
            for (int j = 0; j < 2; ++j)
                bw[j] = *(const bf16x8*)&Bt[wc * 32 + j * 16 + l16][ks * 32 + lk * 8];
#pragma unroll
            for (int mi = 0; mi < 2; ++mi)
#pragma unroll
                for (int nf = 0; nf < 2; ++nf)
                    acc[mi][nf] = mfma16(af[mi], bw[nf], acc[mi][nf]);
        }
        __syncthreads();
    }

    if (z <= 1) {
        short* outp = (z == 0) ? qt : kt;
        const float scl = (z == 0) ? QSCALE : 1.f;
#pragma unroll
        for (int mi = 0; mi < 2; ++mi)
#pragma unroll
            for (int q = 0; q < 4; ++q) {
                const int r = row0 + wr * 32 + mi * 16 + lk * 4 + q;
                const int b = r >> 10, n = r & 1023;
#pragma unroll
                for (int nf = 0; nf < 2; ++nf) {
                    const int o = col0 + wc * 32 + nf * 16 + l16;
                    const int h = o >> 6, s = (o >> 5) & 1, ii = o & 31;
                    float y = (acc[mi][nf][q] + bias[o]) * scl;
                    outp[(((size_t)((b * HH + h) * 2 + s)) << 15) + n * 32 + ii] = f2bf(y);
                }
            }
    } else {
        // transpose through LDS: T[col-in-block 0..63][row-in-block 0..127]
#pragma unroll
        for (int mi = 0; mi < 2; ++mi)
#pragma unroll
            for (int nf = 0; nf < 2; ++nf)
#pragma unroll
                for (int q = 0; q < 4; ++q) {
                    const int c = wc * 32 + nf * 16 + l16;
                    const int r = wr * 32 + mi * 16 + lk * 4 + q;
                    T[c][r] = f2bf(acc[mi][nf][q] + bias[col0 + c]);
                }
        __syncthreads();
        const int b  = row0 >> 10, n0 = row0 & 1023;
        const int c  = tid >> 3, seg = tid & 7;    // 8 threads/col, 16 rows each
        const int oc = col0 + c, h = oc >> 6, d = oc & 63;
        const size_t base = (((size_t)(b * HH + h)) * 64 + d) * NN + n0 + seg * 16;
#pragma unroll
        for (int u = 0; u < 2; ++u)
            *(uint4*)&vt[base + u * 8] = *(const uint4*)&T[c][seg * 16 + u * 8];
    }
}

// ---------------------------------------------------------------------------
// Attention core (champion). flat grid 256; 512 thr / 8 waves.
// ---------------------------------------------------------------------------
__global__ __launch_bounds__(512) void attn_mfma(
    const short* __restrict__ qt, const short* __restrict__ kt,
    const short* __restrict__ vtg, short* __restrict__ aoh, short* __restrict__ aol)
{
    __shared__ __align__(16) short LDS_[17408];           // 34,816 B
    short* KsB = LDS_;                                    // [2 sig][64][40]
    short* VtB = LDS_ + 5120;                             // [64][72]
    float* OsB = (float*)LDS_;                            // [128][68] epilogue overlay

#define KS(ss, r, c)  KsB[((ss) * 64 + (r)) * 40 + (c)]
#define VT(d, m)      VtB[(d) * 72 + (m)]
#define OS(n, d)      OsB[(n) * 68 + (d)]

    const int L = xcd_logical(blockIdx.x, 256);
    const int bh = L >> 3;
    const int n0 = (L & 7) * 128;

    const int tid  = threadIdx.x;
    const int lane = tid & 63;
    const int wid  = tid >> 6;
    const int s  = wid >> 2;
    const int hq = wid & 3;
    const int l16 = lane & 15, lk = lane >> 4;

    bf16x8 qf[2];
#pragma unroll
    for (int nf = 0; nf < 2; ++nf)
        qf[nf] = *(const bf16x8*)&qt[((size_t)(bh * 2 + s) * NN + n0 + hq * 32 + nf * 16 + l16) * 32 + lk * 8];

    const int kss = tid >> 8, kj = tid & 255, kr = kj >> 2, kc8 = (kj & 3) << 3;
    const int vd = tid >> 3, vc8 = (tid & 7) << 3;

    uint4 kpf, vpf;
    auto load_tiles = [&](int m0) {
        kpf = *(const uint4*)&kt[((size_t)(bh * 2 + kss) * NN + m0 + kr) * 32 + kc8];
        vpf = *(const uint4*)&vtg[((size_t)(bh * 64 + vd)) * NN + m0 + vc8];
    };
    auto commit_tiles = [&]() {
        *(uint4*)&KS(kss, kr, kc8) = kpf;
        *(uint4*)&VT(vd, vc8) = vpf;
    };

    f32x4 accn[2][4];
#pragma unroll
    for (int nf = 0; nf < 2; ++nf)
#pragma unroll
        for (int df = 0; df < 4; ++df) accn[nf][df] = (f32x4){0.f, 0.f, 0.f, 0.f};
    float den[2] = {0.f, 0.f};

    load_tiles(0);

    for (int t = 0; t < NT; ++t) {
        commit_tiles();
        if (t + 1 < NT) load_tiles((t + 1) * 64);
        __syncthreads();                            // barrier 1

        bf16x8 kf[4], vf[2][4];
#pragma unroll
        for (int mf = 0; mf < 4; ++mf)
            kf[mf] = *(const bf16x8*)&KS(s, mf * 16 + l16, lk * 8);
#pragma unroll
        for (int kb = 0; kb < 2; ++kb)
#pragma unroll
            for (int df = 0; df < 4; ++df)
                vf[kb][df] = *(const bf16x8*)&VT(df * 16 + l16, kb * 32 + lk * 8);

#pragma unroll
        for (int nf = 0; nf < 2; ++nf) {
            unsigned c01[4], c23[4];
#pragma unroll
            for (int mf = 0; mf < 4; ++mf) {
                f32x4 st = mfma16(kf[mf], qf[nf], (f32x4){0.f, 0.f, 0.f, 0.f});
                float p0 = 1.f + st[0] * (1.f + 0.5f * st[0]);
                float p1 = 1.f + st[1] * (1.f + 0.5f * st[1]);
                float p2 = 1.f + st[2] * (1.f + 0.5f * st[2]);
                float p3 = 1.f + st[3] * (1.f + 0.5f * st[3]);
                den[nf] += (p0 + p1) + (p2 + p3);
                asm("v_cvt_pk_bf16_f32 %0, %1, %2" : "=v"(c01[mf]) : "v"(p0), "v"(p1));
                asm("v_cvt_pk_bf16_f32 %0, %1, %2" : "=v"(c23[mf]) : "v"(p2), "v"(p3));
            }
#pragma unroll
            for (int kb = 0; kb < 2; ++kb) {
                u32x2 x0 = __builtin_amdgcn_permlane32_swap(c01[2 * kb], c01[2 * kb + 1], 0, 0);
                u32x2 w02 = __builtin_amdgcn_permlane16_swap(x0.x, x0.y, 0, 0);
                u32x2 x1 = __builtin_amdgcn_permlane32_swap(c23[2 * kb], c23[2 * kb + 1], 0, 0);
                u32x2 w13 = __builtin_amdgcn_permlane16_swap(x1.x, x1.y, 0, 0);
                uint4 u = {w02.x, w13.x, w02.y, w13.y};
                bf16x8 pf = *(bf16x8*)&u;
#pragma unroll
                for (int df = 0; df < 4; ++df)
                    accn[nf][df] = mfma16(pf, vf[kb][df], accn[nf][df]);
            }
        }
        __syncthreads();                            // barrier 2
    }

    float invq[2][4];
#pragma unroll
    for (int nf = 0; nf < 2; ++nf) {
        float d = den[nf];
        d += __shfl_xor(d, 16, 64);
        d += __shfl_xor(d, 32, 64);
#pragma unroll
        for (int q = 0; q < 4; ++q)
            invq[nf][q] = 0.5f / (__shfl(d, (lane & 48) + lk * 4 + q, 64) + 1e-6f);
    }

    if (s == 0) {
#pragma unroll
        for (int nf = 0; nf < 2; ++nf)
#pragma unroll
            for (int q = 0; q < 4; ++q)
#pragma unroll
                for (int df = 0; df < 4; ++df)
                    OS(hq * 32 + nf * 16 + lk * 4 + q, df * 16 + l16) =
                        accn[nf][df][q] * invq[nf][q];
    }
    __syncthreads();
    if (s == 1) {
        const int b = bh >> 4, h = bh & 15;
#pragma unroll
        for (int nf = 0; nf < 2; ++nf)
#pragma unroll
            for (int q = 0; q < 4; ++q) {
                const int n = hq * 32 + nf * 16 + lk * 4 + q;
#pragma unroll
                for (int df = 0; df < 4; ++df) {
                    const int d = df * 16 + l16;
                    float o = OS(n, d) + accn[nf][df][q] * invq[nf][q];
                    size_t addr = ((size_t)b * NN + n0 + n) * CC + h * 64 + d;
                    short hi = f2bf(o);
                    aoh[addr] = hi;
                    aol[addr] = f2bf(o - bf2f(hi));
                }
            }
    }
#undef KS
#undef VT
#undef OS
}

// ---------------------------------------------------------------------------
// Output projection, 3-term split-bf16, BK=32 (champion). 256 thr / 4 waves.
// flat grid 512; logical = row*16 + col (XCD-chunked).
// ---------------------------------------------------------------------------
__global__ __launch_bounds__(256) void wo_proj(
    const short* __restrict__ aoh, const short* __restrict__ aol,
    const float* __restrict__ Wo, const float* __restrict__ bo,
    float* __restrict__ outp)
{
    __shared__ short Ah[64][40], Al[64][40], Wh[64][40], Wl[64][40];

    const int L = xcd_logical(blockIdx.x, 512);
    const int row0 = (L >> 4) * 64;
    const int col0 = (L & 15) * 64;

    const int tid  = threadIdx.x;
    const int lane = tid & 63, wave = tid >> 6;
    const int wr = wave >> 1, wc = wave & 1;
    const int l16 = lane & 15, lk = lane >> 4;

    const int ar  = tid >> 2, ac8 = (tid & 3) << 3;
    const int wrr = tid >> 3, wc4 = (tid & 7) << 2;

    uint4 ph, pl;
    float4 pw[2];
    ph = *(const uint4*)&aoh[(size_t)(row0 + ar) * CC + ac8];
    pl = *(const uint4*)&aol[(size_t)(row0 + ar) * CC + ac8];
#pragma unroll
    for (int p = 0; p < 2; ++p)
        pw[p] = *(const float4*)&Wo[(size_t)(col0 + p * 32 + wrr) * CC + wc4];

    f32x4 acc[2][2];
#pragma unroll
    for (int i = 0; i < 2; ++i)
#pragma unroll
        for (int j = 0; j < 2; ++j) acc[i][j] = (f32x4){0.f, 0.f, 0.f, 0.f};

    for (int k0 = 0; k0 < CC; k0 += 32) {
        *(uint4*)&Ah[ar][ac8] = ph;
        *(uint4*)&Al[ar][ac8] = pl;
#pragma unroll
        for (int p = 0; p < 2; ++p) {
            float v[4] = {pw[p].x, pw[p].y, pw[p].z, pw[p].w};
            unsigned short hs[4], ls[4];
#pragma unroll
            for (int j = 0; j < 4; ++j) {
                short hv = f2bf(v[j]);
                hs[j] = (unsigned short)hv;
                ls[j] = (unsigned short)f2bf(v[j] - bf2f(hv));
            }
            *(ushort4*)&Wh[p * 32 + wrr][wc4] = (ushort4){hs[0], hs[1], hs[2], hs[3]};
            *(ushort4*)&Wl[p * 32 + wrr][wc4] = (ushort4){ls[0], ls[1], ls[2], ls[3]};
        }
        if (k0 + 32 < CC) {
            ph = *(const uint4*)&aoh[(size_t)(row0 + ar) * CC + k0 + 32 + ac8];
            pl = *(const uint4*)&aol[(size_t)(row0 + ar) * CC + k0 + 32 + ac8];
#pragma unroll
            for (int p = 0; p < 2; ++p)
                pw[p] = *(const float4*)&Wo[(size_t)(col0 + p * 32 + wrr) * CC + k0 + 32 + wc4];
        }
        __syncthreads();
        bf16x8 ah[2], al[2], wh[2], wl[2];
#pragma unroll
        for (int i = 0; i < 2; ++i) {
            ah[i] = *(const bf16x8*)&Ah[wr * 32 + i * 16 + l16][lk * 8];
            al[i] = *(const bf16x8*)&Al[wr * 32 + i * 16 + l16][lk * 8];
            wh[i] = *(const bf16x8*)&Wh[wc * 32 + i * 16 + l16][lk * 8];
            wl[i] = *(const bf16x8*)&Wl[wc * 32 + i * 16 + l16][lk * 8];
        }
#pragma unroll
        for (int mi = 0; mi < 2; ++mi)
#pragma unroll
            for (int nj = 0; nj < 2; ++nj) {
                acc[mi][nj] = mfma16(ah[mi], wh[nj], acc[mi][nj]);
                acc[mi][nj] = mfma16(ah[mi], wl[nj], acc[mi][nj]);
                acc[mi][nj] = mfma16(al[mi], wh[nj], acc[mi][nj]);
            }
        __syncthreads();
    }

#pragma unroll
    for (int mi = 0; mi < 2; ++mi)
#pragma unroll
        for (int q = 0; q < 4; ++q) {
            const int r = row0 + wr * 32 + mi * 16 + lk * 4 + q;
#pragma unroll
            for (int nj = 0; nj < 2; ++nj) {
                const int o = col0 + wc * 32 + nj * 16 + l16;
                outp[(size_t)r * CC + o] = acc[mi][nj][q] + bo[o];
            }
        }
}

extern "C" void kernel_launch(void* const* d_in, const int* in_sizes, int n_in,
                              void* d_out, int out_size, void* d_ws, size_t ws_size,
                              hipStream_t stream) {
    const float* query = (const float*)d_in[0];
    const float* key_  = (const float*)d_in[1];
    const float* value = (const float*)d_in[2];
    const float* Wq = (const float*)d_in[3];
    const float* bq = (const float*)d_in[4];
    const float* Wk = (const float*)d_in[5];
    const float* bk = (const float*)d_in[6];
    const float* Wv = (const float*)d_in[7];
    const float* bv = (const float*)d_in[8];
    const float* Wo = (const float*)d_in[9];
    const float* bo = (const float*)d_in[10];
    float* out = (float*)d_out;

    short* qt  = (short*)d_ws;                 // 4 MB  [b][h][s][n][32]
    short* kt  = qt  + ((size_t)1 << 21);      // 4 MB  [b][h][s][m][32]
    short* vt  = kt  + ((size_t)1 << 21);      // 4 MB  [b][h][d][m]
    short* aoh = vt  + ((size_t)1 << 21);      // 4 MB  attn out hi
    short* aol = aoh + ((size_t)1 << 21);      // 4 MB  attn out lo

    qkv_proj<<<dim3(768), dim3(512), 0, stream>>>(query, key_, value, Wq, Wk, Wv,
                                                  bq, bk, bv, qt, kt, vt);
    attn_mfma<<<dim3(256), dim3(512), 0, stream>>>(qt, kt, vt, aoh, aol);
    wo_proj<<<dim3(512), dim3(256), 0, stream>>>(aoh, aol, Wo, bo, out);
}

// Round 33
// 78.220 us; speedup vs baseline: 1.0016x; 1.0016x over previous
//
#include <hip/hip_runtime.h>
#include <hip/hip_bf16.h>

#define CC 1024
#define NN 1024
#define BB 2
#define HH 16
#define NT (NN / 64)
#define QSCALE 0.17677669529663687f  // 1/sqrt(32)

typedef short bf16x8 __attribute__((ext_vector_type(8)));
typedef float f32x4  __attribute__((ext_vector_type(4)));
typedef unsigned int u32x2 __attribute__((ext_vector_type(2)));

__device__ __forceinline__ f32x4 mfma16(bf16x8 a, bf16x8 b, f32x4 c) {
    return __builtin_amdgcn_mfma_f32_16x16x32_bf16(a, b, c, 0, 0, 0);
}
__device__ __forceinline__ short f2bf(float x) {
    __hip_bfloat16 h = __float2bfloat16(x);
    return *reinterpret_cast<short*>(&h);
}
__device__ __forceinline__ float bf2f(short s) {
    __hip_bfloat16 h;
    *reinterpret_cast<short*>(&h) = s;
    return __bfloat162float(h);
}
// XCD-chunked swizzle (bijective when nwg % 8 == 0).
__device__ __forceinline__ int xcd_logical(int hw, int nwg) {
    return (hw & 7) * (nwg >> 3) + (hw >> 3);
}

// ---------------------------------------------------------------------------
// Fused QKV projection (champion): tile 128x64, BK=64, 512 thr / 8 waves,
// per-wave 32x32, grid 768 (XCD-chunked), 6 waves/SIMD.
// ---------------------------------------------------------------------------
__global__ __launch_bounds__(512) void qkv_proj(
    const float* __restrict__ xq, const float* __restrict__ xk, const float* __restrict__ xv,
    const float* __restrict__ wq, const float* __restrict__ wk, const float* __restrict__ wv,
    const float* __restrict__ bq, const float* __restrict__ bk, const float* __restrict__ bv,
    short* __restrict__ qt, short* __restrict__ kt, short* __restrict__ vt)
{
    __shared__ short LD[13824];                        // 27,648 B
    short (*A)[72]  = (short(*)[72])LD;                // 128 x 72
    short (*Bt)[72] = (short(*)[72])(LD + 128 * 72);   // 64 x 72
    short (*T)[136] = (short(*)[136])LD;               // z=2 overlay: 64 x 136

    const int L = xcd_logical(blockIdx.x, 768);
    const int z = L >> 8;                 // /256
    const int rem = L & 255;
    const int row0 = (rem >> 4) * 128;    // 16 row-blocks
    const int col0 = (rem & 15) * 64;     // 16 col-blocks

    const int tid  = threadIdx.x;
    const int lane = tid & 63, wid = tid >> 6;     // 8 waves
    const int wr = wid >> 1, wc = wid & 1;         // 4 x 2: per-wave 32 x 32
    const int l16 = lane & 15, lk = lane >> 4;

    const float* X    = (z == 0) ? xq : (z == 1) ? xk : xv;
    const float* W    = (z == 0) ? wq : (z == 1) ? wk : wv;
    const float* bias = (z == 0) ? bq : (z == 1) ? bk : bv;

    const int str = tid >> 4;          // 0..31
    const int stc = (tid & 15) << 2;   // 0..60

    float4 pa[4], pb[2];
#pragma unroll
    for (int p = 0; p < 4; ++p)
        pa[p] = *(const float4*)&X[(size_t)(row0 + p * 32 + str) * CC + stc];
#pragma unroll
    for (int p = 0; p < 2; ++p)
        pb[p] = *(const float4*)&W[(size_t)(col0 + p * 32 + str) * CC + stc];

    f32x4 acc[2][2];
#pragma unroll
    for (int i = 0; i < 2; ++i)
#pragma unroll
        for (int j = 0; j < 2; ++j) acc[i][j] = (f32x4){0.f, 0.f, 0.f, 0.f};

    for (int k0 = 0; k0 < CC; k0 += 64) {
#pragma unroll
        for (int p = 0; p < 4; ++p) {
            ushort4 ua = { (unsigned short)f2bf(pa[p].x), (unsigned short)f2bf(pa[p].y),
                           (unsigned short)f2bf(pa[p].z), (unsigned short)f2bf(pa[p].w) };
            *(ushort4*)&A[p * 32 + str][stc] = ua;
        }
#pragma unroll
        for (int p = 0; p < 2; ++p) {
            ushort4 ub = { (unsigned short)f2bf(pb[p].x), (unsigned short)f2bf(pb[p].y),
                           (unsigned short)f2bf(pb[p].z), (unsigned short)f2bf(pb[p].w) };
            *(ushort4*)&Bt[p * 32 + str][stc] = ub;
        }
        if (k0 + 64 < CC) {
#pragma unroll
            for (int p = 0; p < 4; ++p)
                pa[p] = *(const float4*)&X[(size_t)(row0 + p * 32 + str) * CC + k0 + 64 + stc];
#pragma unroll
            for (int p = 0; p < 2; ++p)
                pb[p] = *(const float4*)&W[(size_t)(col0 + p * 32 + str) * CC + k0 + 64 + stc];
        }
        __syncthreads();
#pragma unroll
        for (int ks = 0; ks < 2; ++ks) {
            bf16x8 af[2], bw[2];
#pragma unroll
            for (int i = 0; i < 2; ++i)
                af[i] = *(const bf16x8*)&A[wr * 32 + i * 16 + l16][ks * 32 + lk * 8];
#pragma unroll
            for (int j = 0; j < 2; ++j)
                bw[j] = *(const bf16x8*)&Bt[wc * 32 + j * 16 + l16][ks * 32 + lk * 8];
#pragma unroll
            for (int mi = 0; mi < 2; ++mi)
#pragma unroll
                for (int nf = 0; nf < 2; ++nf)
                    acc[mi][nf] = mfma16(af[mi], bw[nf], acc[mi][nf]);
        }
        __syncthreads();
    }

    if (z <= 1) {
        short* outp = (z == 0) ? qt : kt;
        const float scl = (z == 0) ? QSCALE : 1.f;
#pragma unroll
        for (int mi = 0; mi < 2; ++mi)
#pragma unroll
            for (int q = 0; q < 4; ++q) {
                const int r = row0 + wr * 32 + mi * 16 + lk * 4 + q;
                const int b = r >> 10, n = r & 1023;
#pragma unroll
                for (int nf = 0; nf < 2; ++nf) {
                    const int o = col0 + wc * 32 + nf * 16 + l16;
                    const int h = o >> 6, s = (o >> 5) & 1, ii = o & 31;
                    float y = (acc[mi][nf][q] + bias[o]) * scl;
                    outp[(((size_t)((b * HH + h) * 2 + s)) << 15) + n * 32 + ii] = f2bf(y);
                }
            }
    } else {
        // transpose through LDS: T[col-in-block 0..63][row-in-block 0..127]
#pragma unroll
        for (int mi = 0; mi < 2; ++mi)
#pragma unroll
            for (int nf = 0; nf < 2; ++nf)
#pragma unroll
                for (int q = 0; q < 4; ++q) {
                    const int c = wc * 32 + nf * 16 + l16;
                    const int r = wr * 32 + mi * 16 + lk * 4 + q;
                    T[c][r] = f2bf(acc[mi][nf][q] + bias[col0 + c]);
                }
        __syncthreads();
        const int b  = row0 >> 10, n0 = row0 & 1023;
        const int c  = tid >> 3, seg = tid & 7;    // 8 threads/col, 16 rows each
        const int oc = col0 + c, h = oc >> 6, d = oc & 63;
        const size_t base = (((size_t)(b * HH + h)) * 64 + d) * NN + n0 + seg * 16;
#pragma unroll
        for (int u = 0; u < 2; ++u)
            *(uint4*)&vt[base + u * 8] = *(const uint4*)&T[c][seg * 16 + u * 8];
    }
}

// ---------------------------------------------------------------------------
// Attention core (champion). flat grid 256; 512 thr / 8 waves.
// ---------------------------------------------------------------------------
__global__ __launch_bounds__(512) void attn_mfma(
    const short* __restrict__ qt, const short* __restrict__ kt,
    const short* __restrict__ vtg, short* __restrict__ aoh, short* __restrict__ aol)
{
    __shared__ __align__(16) short LDS_[17408];           // 34,816 B
    short* KsB = LDS_;                                    // [2 sig][64][40]
    short* VtB = LDS_ + 5120;                             // [64][72]
    float* OsB = (float*)LDS_;                            // [128][68] epilogue overlay

#define KS(ss, r, c)  KsB[((ss) * 64 + (r)) * 40 + (c)]
#define VT(d, m)      VtB[(d) * 72 + (m)]
#define OS(n, d)      OsB[(n) * 68 + (d)]

    const int L = xcd_logical(blockIdx.x, 256);
    const int bh = L >> 3;
    const int n0 = (L & 7) * 128;

    const int tid  = threadIdx.x;
    const int lane = tid & 63;
    const int wid  = tid >> 6;
    const int s  = wid >> 2;
    const int hq = wid & 3;
    const int l16 = lane & 15, lk = lane >> 4;

    bf16x8 qf[2];
#pragma unroll
    for (int nf = 0; nf < 2; ++nf)
        qf[nf] = *(const bf16x8*)&qt[((size_t)(bh * 2 + s) * NN + n0 + hq * 32 + nf * 16 + l16) * 32 + lk * 8];

    const int kss = tid >> 8, kj = tid & 255, kr = kj >> 2, kc8 = (kj & 3) << 3;
    const int vd = tid >> 3, vc8 = (tid & 7) << 3;

    uint4 kpf, vpf;
    auto load_tiles = [&](int m0) {
        kpf = *(const uint4*)&kt[((size_t)(bh * 2 + kss) * NN + m0 + kr) * 32 + kc8];
        vpf = *(const uint4*)&vtg[((size_t)(bh * 64 + vd)) * NN + m0 + vc8];
    };
    auto commit_tiles = [&]() {
        *(uint4*)&KS(kss, kr, kc8) = kpf;
        *(uint4*)&VT(vd, vc8) = vpf;
    };

    f32x4 accn[2][4];
#pragma unroll
    for (int nf = 0; nf < 2; ++nf)
#pragma unroll
        for (int df = 0; df < 4; ++df) accn[nf][df] = (f32x4){0.f, 0.f, 0.f, 0.f};
    float den[2] = {0.f, 0.f};

    load_tiles(0);

    for (int t = 0; t < NT; ++t) {
        commit_tiles();
        if (t + 1 < NT) load_tiles((t + 1) * 64);
        __syncthreads();                            // barrier 1

        bf16x8 kf[4], vf[2][4];
#pragma unroll
        for (int mf = 0; mf < 4; ++mf)
            kf[mf] = *(const bf16x8*)&KS(s, mf * 16 + l16, lk * 8);
#pragma unroll
        for (int kb = 0; kb < 2; ++kb)
#pragma unroll
            for (int df = 0; df < 4; ++df)
                vf[kb][df] = *(const bf16x8*)&VT(df * 16 + l16, kb * 32 + lk * 8);

#pragma unroll
        for (int nf = 0; nf < 2; ++nf) {
            unsigned c01[4], c23[4];
#pragma unroll
            for (int mf = 0; mf < 4; ++mf) {
                f32x4 st = mfma16(kf[mf], qf[nf], (f32x4){0.f, 0.f, 0.f, 0.f});
                float p0 = 1.f + st[0] * (1.f + 0.5f * st[0]);
                float p1 = 1.f + st[1] * (1.f + 0.5f * st[1]);
                float p2 = 1.f + st[2] * (1.f + 0.5f * st[2]);
                float p3 = 1.f + st[3] * (1.f + 0.5f * st[3]);
                den[nf] += (p0 + p1) + (p2 + p3);
                asm("v_cvt_pk_bf16_f32 %0, %1, %2" : "=v"(c01[mf]) : "v"(p0), "v"(p1));
                asm("v_cvt_pk_bf16_f32 %0, %1, %2" : "=v"(c23[mf]) : "v"(p2), "v"(p3));
            }
#pragma unroll
            for (int kb = 0; kb < 2; ++kb) {
                u32x2 x0 = __builtin_amdgcn_permlane32_swap(c01[2 * kb], c01[2 * kb + 1], 0, 0);
                u32x2 w02 = __builtin_amdgcn_permlane16_swap(x0.x, x0.y, 0, 0);
                u32x2 x1 = __builtin_amdgcn_permlane32_swap(c23[2 * kb], c23[2 * kb + 1], 0, 0);
                u32x2 w13 = __builtin_amdgcn_permlane16_swap(x1.x, x1.y, 0, 0);
                uint4 u = {w02.x, w13.x, w02.y, w13.y};
                bf16x8 pf = *(bf16x8*)&u;
#pragma unroll
                for (int df = 0; df < 4; ++df)
                    accn[nf][df] = mfma16(pf, vf[kb][df], accn[nf][df]);
            }
        }
        __syncthreads();                            // barrier 2
    }

    float invq[2][4];
#pragma unroll
    for (int nf = 0; nf < 2; ++nf) {
        float d = den[nf];
        d += __shfl_xor(d, 16, 64);
        d += __shfl_xor(d, 32, 64);
#pragma unroll
        for (int q = 0; q < 4; ++q)
            invq[nf][q] = 0.5f / (__shfl(d, (lane & 48) + lk * 4 + q, 64) + 1e-6f);
    }

    if (s == 0) {
#pragma unroll
        for (int nf = 0; nf < 2; ++nf)
#pragma unroll
            for (int q = 0; q < 4; ++q)
#pragma unroll
                for (int df = 0; df < 4; ++df)
                    OS(hq * 32 + nf * 16 + lk * 4 + q, df * 16 + l16) =
                        accn[nf][df][q] * invq[nf][q];
    }
    __syncthreads();
    if (s == 1) {
        const int b = bh >> 4, h = bh & 15;
#pragma unroll
        for (int nf = 0; nf < 2; ++nf)
#pragma unroll
            for (int q = 0; q < 4; ++q) {
                const int n = hq * 32 + nf * 16 + lk * 4 + q;
#pragma unroll
                for (int df = 0; df < 4; ++df) {
                    const int d = df * 16 + l16;
                    float o = OS(n, d) + accn[nf][df][q] * invq[nf][q];
                    size_t addr = ((size_t)b * NN + n0 + n) * CC + h * 64 + d;
                    short hi = f2bf(o);
                    aoh[addr] = hi;
                    aol[addr] = f2bf(o - bf2f(hi));
                }
            }
    }
#undef KS
#undef VT
#undef OS
}

// ---------------------------------------------------------------------------
// Output projection, 3-term split-bf16, BK=32 (champion). 256 thr / 4 waves.
// flat grid 512; logical = row*16 + col (XCD-chunked).
// ---------------------------------------------------------------------------
__global__ __launch_bounds__(256) void wo_proj(
    const short* __restrict__ aoh, const short* __restrict__ aol,
    const float* __restrict__ Wo, const float* __restrict__ bo,
    float* __restrict__ outp)
{
    __shared__ short Ah[64][40], Al[64][40], Wh[64][40], Wl[64][40];

    const int L = xcd_logical(blockIdx.x, 512);
    const int row0 = (L >> 4) * 64;
    const int col0 = (L & 15) * 64;

    const int tid  = threadIdx.x;
    const int lane = tid & 63, wave = tid >> 6;
    const int wr = wave >> 1, wc = wave & 1;
    const int l16 = lane & 15, lk = lane >> 4;

    const int ar  = tid >> 2, ac8 = (tid & 3) << 3;
    const int wrr = tid >> 3, wc4 = (tid & 7) << 2;

    uint4 ph, pl;
    float4 pw[2];
    ph = *(const uint4*)&aoh[(size_t)(row0 + ar) * CC + ac8];
    pl = *(const uint4*)&aol[(size_t)(row0 + ar) * CC + ac8];
#pragma unroll
    for (int p = 0; p < 2; ++p)
        pw[p] = *(const float4*)&Wo[(size_t)(col0 + p * 32 + wrr) * CC + wc4];

    f32x4 acc[2][2];
#pragma unroll
    for (int i = 0; i < 2; ++i)
#pragma unroll
        for (int j = 0; j < 2; ++j) acc[i][j] = (f32x4){0.f, 0.f, 0.f, 0.f};

    for (int k0 = 0; k0 < CC; k0 += 32) {
        *(uint4*)&Ah[ar][ac8] = ph;
        *(uint4*)&Al[ar][ac8] = pl;
#pragma unroll
        for (int p = 0; p < 2; ++p) {
            float v[4] = {pw[p].x, pw[p].y, pw[p].z, pw[p].w};
            unsigned short hs[4], ls[4];
#pragma unroll
            for (int j = 0; j < 4; ++j) {
                short hv = f2bf(v[j]);
                hs[j] = (unsigned short)hv;
                ls[j] = (unsigned short)f2bf(v[j] - bf2f(hv));
            }
            *(ushort4*)&Wh[p * 32 + wrr][wc4] = (ushort4){hs[0], hs[1], hs[2], hs[3]};
            *(ushort4*)&Wl[p * 32 + wrr][wc4] = (ushort4){ls[0], ls[1], ls[2], ls[3]};
        }
        if (k0 + 32 < CC) {
            ph = *(const uint4*)&aoh[(size_t)(row0 + ar) * CC + k0 + 32 + ac8];
            pl = *(const uint4*)&aol[(size_t)(row0 + ar) * CC + k0 + 32 + ac8];
#pragma unroll
            for (int p = 0; p < 2; ++p)
                pw[p] = *(const float4*)&Wo[(size_t)(col0 + p * 32 + wrr) * CC + k0 + 32 + wc4];
        }
        __syncthreads();
        bf16x8 ah[2], al[2], wh[2], wl[2];
#pragma unroll
        for (int i = 0; i < 2; ++i) {
            ah[i] = *(const bf16x8*)&Ah[wr * 32 + i * 16 + l16][lk * 8];
            al[i] = *(const bf16x8*)&Al[wr * 32 + i * 16 + l16][lk * 8];
            wh[i] = *(const bf16x8*)&Wh[wc * 32 + i * 16 + l16][lk * 8];
            wl[i] = *(const bf16x8*)&Wl[wc * 32 + i * 16 + l16][lk * 8];
        }
#pragma unroll
        for (int mi = 0; mi < 2; ++mi)
#pragma unroll
            for (int nj = 0; nj < 2; ++nj) {
                acc[mi][nj] = mfma16(ah[mi], wh[nj], acc[mi][nj]);
                acc[mi][nj] = mfma16(ah[mi], wl[nj], acc[mi][nj]);
                acc[mi][nj] = mfma16(al[mi], wh[nj], acc[mi][nj]);
            }
        __syncthreads();
    }

#pragma unroll
    for (int mi = 0; mi < 2; ++mi)
#pragma unroll
        for (int q = 0; q < 4; ++q) {
            const int r = row0 + wr * 32 + mi * 16 + lk * 4 + q;
#pragma unroll
            for (int nj = 0; nj < 2; ++nj) {
                const int o = col0 + wc * 32 + nj * 16 + l16;
                outp[(size_t)r * CC + o] = acc[mi][nj][q] + bo[o];
            }
        }
}

extern "C" void kernel_launch(void* const* d_in, const int* in_sizes, int n_in,
                              void* d_out, int out_size, void* d_ws, size_t ws_size,
                              hipStream_t stream) {
    const float* query = (const float*)d_in[0];
    const float* key_  = (const float*)d_in[1];
    const float* value = (const float*)d_in[2];
    const float* Wq = (const float*)d_in[3];
    const float* bq = (const float*)d_in[4];
    const float* Wk = (const float*)d_in[5];
    const float* bk = (const float*)d_in[6];
    const float* Wv = (const float*)d_in[7];
    const float* bv = (const float*)d_in[8];
    const float* Wo = (const float*)d_in[9];
    const float* bo = (const float*)d_in[10];
    float* out = (float*)d_out;

    short* qt  = (short*)d_ws;                 // 4 MB  [b][h][s][n][32]
    short* kt  = qt  + ((size_t)1 << 21);      // 4 MB  [b][h][s][m][32]
    short* vt  = kt  + ((size_t)1 << 21);      // 4 MB  [b][h][d][m]
    short* aoh = vt  + ((size_t)1 << 21);      // 4 MB  attn out hi
    short* aol = aoh + ((size_t)1 << 21);      // 4 MB  attn out lo

    qkv_proj<<<dim3(768), dim3(512), 0, stream>>>(query, key_, value, Wq, Wk, Wv,
                                                  bq, bk, bv, qt, kt, vt);
    attn_mfma<<<dim3(256), dim3(512), 0, stream>>>(qt, kt, vt, aoh, aol);
    wo_proj<<<dim3(512), dim3(256), 0, stream>>>(aoh, aol, Wo, bo, out);
}

// Round 34
// 78.152 us; speedup vs baseline: 1.0024x; 1.0009x over previous
//
#include <hip/hip_runtime.h>
#include <hip/hip_bf16.h>

#define CC 1024
#define NN 1024
#define BB 2
#define HH 16
#define NT (NN / 64)
#define QSCALE 0.17677669529663687f  // 1/sqrt(32)

typedef short bf16x8 __attribute__((ext_vector_type(8)));
typedef float f32x4  __attribute__((ext_vector_type(4)));
typedef unsigned int u32x2 __attribute__((ext_vector_type(2)));

__device__ __forceinline__ f32x4 mfma16(bf16x8 a, bf16x8 b, f32x4 c) {
    return __builtin_amdgcn_mfma_f32_16x16x32_bf16(a, b, c, 0, 0, 0);
}
__device__ __forceinline__ short f2bf(float x) {
    __hip_bfloat16 h = __float2bfloat16(x);
    return *reinterpret_cast<short*>(&h);
}
__device__ __forceinline__ float bf2f(short s) {
    __hip_bfloat16 h;
    *reinterpret_cast<short*>(&h) = s;
    return __bfloat162float(h);
}
// XCD-chunked swizzle (bijective when nwg % 8 == 0).
__device__ __forceinline__ int xcd_logical(int hw, int nwg) {
    return (hw & 7) * (nwg >> 3) + (hw >> 3);
}

// ---------------------------------------------------------------------------
// Fused QKV projection (champion): tile 128x64, BK=64, 512 thr / 8 waves,
// per-wave 32x32, grid 768 (XCD-chunked), 6 waves/SIMD.
// ---------------------------------------------------------------------------
__global__ __launch_bounds__(512) void qkv_proj(
    const float* __restrict__ xq, const float* __restrict__ xk, const float* __restrict__ xv,
    const float* __restrict__ wq, const float* __restrict__ wk, const float* __restrict__ wv,
    const float* __restrict__ bq, const float* __restrict__ bk, const float* __restrict__ bv,
    short* __restrict__ qt, short* __restrict__ kt, short* __restrict__ vt)
{
    __shared__ short LD[13824];                        // 27,648 B
    short (*A)[72]  = (short(*)[72])LD;                // 128 x 72
    short (*Bt)[72] = (short(*)[72])(LD + 128 * 72);   // 64 x 72
    short (*T)[136] = (short(*)[136])LD;               // z=2 overlay: 64 x 136

    const int L = xcd_logical(blockIdx.x, 768);
    const int z = L >> 8;                 // /256
    const int rem = L & 255;
    const int row0 = (rem >> 4) * 128;    // 16 row-blocks
    const int col0 = (rem & 15) * 64;     // 16 col-blocks

    const int tid  = threadIdx.x;
    const int lane = tid & 63, wid = tid >> 6;     // 8 waves
    const int wr = wid >> 1, wc = wid & 1;         // 4 x 2: per-wave 32 x 32
    const int l16 = lane & 15, lk = lane >> 4;

    const float* X    = (z == 0) ? xq : (z == 1) ? xk : xv;
    const float* W    = (z == 0) ? wq : (z == 1) ? wk : wv;
    const float* bias = (z == 0) ? bq : (z == 1) ? bk : bv;

    const int str = tid >> 4;          // 0..31
    const int stc = (tid & 15) << 2;   // 0..60

    float4 pa[4], pb[2];
#pragma unroll
    for (int p = 0; p < 4; ++p)
        pa[p] = *(const float4*)&X[(size_t)(row0 + p * 32 + str) * CC + stc];
#pragma unroll
    for (int p = 0; p < 2; ++p)
        pb[p] = *(const float4*)&W[(size_t)(col0 + p * 32 + str) * CC + stc];

    f32x4 acc[2][2];
#pragma unroll
    for (int i = 0; i < 2; ++i)
#pragma unroll
        for (int j = 0; j < 2; ++j) acc[i][j] = (f32x4){0.f, 0.f, 0.f, 0.f};

    for (int k0 = 0; k0 < CC; k0 += 64) {
#pragma unroll
        for (int p = 0; p < 4; ++p) {
            ushort4 ua = { (unsigned short)f2bf(pa[p].x), (unsigned short)f2bf(pa[p].y),
                           (unsigned short)f2bf(pa[p].z), (unsigned short)f2bf(pa[p].w) };
            *(ushort4*)&A[p * 32 + str][stc] = ua;
        }
#pragma unroll
        for (int p = 0; p < 2; ++p) {
            ushort4 ub = { (unsigned short)f2bf(pb[p].x), (unsigned short)f2bf(pb[p].y),
                           (unsigned short)f2bf(pb[p].z), (unsigned short)f2bf(pb[p].w) };
            *(ushort4*)&Bt[p * 32 + str][stc] = ub;
        }
        if (k0 + 64 < CC) {
#pragma unroll
            for (int p = 0; p < 4; ++p)
                pa[p] = *(const float4*)&X[(size_t)(row0 + p * 32 + str) * CC + k0 + 64 + stc];
#pragma unroll
            for (int p = 0; p < 2; ++p)
                pb[p] = *(const float4*)&W[(size_t)(col0 + p * 32 + str) * CC + k0 + 64 + stc];
        }
        __syncthreads();
#pragma unroll
        for (int ks = 0; ks < 2; ++ks) {
            bf16x8 af[2], bw[2];
#pragma unroll
            for (int i = 0; i < 2; ++i)
                af[i] = *(const bf16x8*)&A[wr * 32 + i * 16 + l16][ks * 32 + lk * 8];
#pragma unroll
            for (int j = 0; j < 2; ++j)
                bw[j] = *(const bf16x8*)&Bt[wc * 32 + j * 16 + l16][ks * 32 + lk * 8];
#pragma unroll
            for (int mi = 0; mi < 2; ++mi)
#pragma unroll
                for (int nf = 0; nf < 2; ++nf)
                    acc[mi][nf] = mfma16(af[mi], bw[nf], acc[mi][nf]);
        }
        __syncthreads();
    }

    if (z <= 1) {
        short* outp = (z == 0) ? qt : kt;
        const float scl = (z == 0) ? QSCALE : 1.f;
#pragma unroll
        for (int mi = 0; mi < 2; ++mi)
#pragma unroll
            for (int q = 0; q < 4; ++q) {
                const int r = row0 + wr * 32 + mi * 16 + lk * 4 + q;
                const int b = r >> 10, n = r & 1023;
#pragma unroll
                for (int nf = 0; nf < 2; ++nf) {
                    const int o = col0 + wc * 32 + nf * 16 + l16;
                    const int h = o >> 6, s = (o >> 5) & 1, ii = o & 31;
                    float y = (acc[mi][nf][q] + bias[o]) * scl;
                    outp[(((size_t)((b * HH + h) * 2 + s)) << 15) + n * 32 + ii] = f2bf(y);
                }
            }
    } else {
        // transpose through LDS: T[col-in-block 0..63][row-in-block 0..127]
#pragma unroll
        for (int mi = 0; mi < 2; ++mi)
#pragma unroll
            for (int nf = 0; nf < 2; ++nf)
#pragma unroll
                for (int q = 0; q < 4; ++q) {
                    const int c = wc * 32 + nf * 16 + l16;
                    const int r = wr * 32 + mi * 16 + lk * 4 + q;
                    T[c][r] = f2bf(acc[mi][nf][q] + bias[col0 + c]);
                }
        __syncthreads();
        const int b  = row0 >> 10, n0 = row0 & 1023;
        const int c  = tid >> 3, seg = tid & 7;    // 8 threads/col, 16 rows each
        const int oc = col0 + c, h = oc >> 6, d = oc & 63;
        const size_t base = (((size_t)(b * HH + h)) * 64 + d) * NN + n0 + seg * 16;
#pragma unroll
        for (int u = 0; u < 2; ++u)
            *(uint4*)&vt[base + u * 8] = *(const uint4*)&T[c][seg * 16 + u * 8];
    }
}

// ---------------------------------------------------------------------------
// Attention core (champion). flat grid 256; 512 thr / 8 waves.
// ---------------------------------------------------------------------------
__global__ __launch_bounds__(512) void attn_mfma(
    const short* __restrict__ qt, const short* __restrict__ kt,
    const short* __restrict__ vtg, short* __restrict__ aoh, short* __restrict__ aol)
{
    __shared__ __align__(16) short LDS_[17408];           // 34,816 B
    short* KsB = LDS_;                                    // [2 sig][64][40]
    short* VtB = LDS_ + 5120;                             // [64][72]
    float* OsB = (float*)LDS_;                            // [128][68] epilogue overlay

#define KS(ss, r, c)  KsB[((ss) * 64 + (r)) * 40 + (c)]
#define VT(d, m)      VtB[(d) * 72 + (m)]
#define OS(n, d)      OsB[(n) * 68 + (d)]

    const int L = xcd_logical(blockIdx.x, 256);
    const int bh = L >> 3;
    const int n0 = (L & 7) * 128;

    const int tid  = threadIdx.x;
    const int lane = tid & 63;
    const int wid  = tid >> 6;
    const int s  = wid >> 2;
    const int hq = wid & 3;
    const int l16 = lane & 15, lk = lane >> 4;

    bf16x8 qf[2];
#pragma unroll
    for (int nf = 0; nf < 2; ++nf)
        qf[nf] = *(const bf16x8*)&qt[((size_t)(bh * 2 + s) * NN + n0 + hq * 32 + nf * 16 + l16) * 32 + lk * 8];

    const int kss = tid >> 8, kj = tid & 255, kr = kj >> 2, kc8 = (kj & 3) << 3;
    const int vd = tid >> 3, vc8 = (tid & 7) << 3;

    uint4 kpf, vpf;
    auto load_tiles = [&](int m0) {
        kpf = *(const uint4*)&kt[((size_t)(bh * 2 + kss) * NN + m0 + kr) * 32 + kc8];
        vpf = *(const uint4*)&vtg[((size_t)(bh * 64 + vd)) * NN + m0 + vc8];
    };
    auto commit_tiles = [&]() {
        *(uint4*)&KS(kss, kr, kc8) = kpf;
        *(uint4*)&VT(vd, vc8) = vpf;
    };

    f32x4 accn[2][4];
#pragma unroll
    for (int nf = 0; nf < 2; ++nf)
#pragma unroll
        for (int df = 0; df < 4; ++df) accn[nf][df] = (f32x4){0.f, 0.f, 0.f, 0.f};
    float den[2] = {0.f, 0.f};

    load_tiles(0);

    for (int t = 0; t < NT; ++t) {
        commit_tiles();
        if (t + 1 < NT) load_tiles((t + 1) * 64);
        __syncthreads();                            // barrier 1

        bf16x8 kf[4], vf[2][4];
#pragma unroll
        for (int mf = 0; mf < 4; ++mf)
            kf[mf] = *(const bf16x8*)&KS(s, mf * 16 + l16, lk * 8);
#pragma unroll
        for (int kb = 0; kb < 2; ++kb)
#pragma unroll
            for (int df = 0; df < 4; ++df)
                vf[kb][df] = *(const bf16x8*)&VT(df * 16 + l16, kb * 32 + lk * 8);

#pragma unroll
        for (int nf = 0; nf < 2; ++nf) {
            unsigned c01[4], c23[4];
#pragma unroll
            for (int mf = 0; mf < 4; ++mf) {
                f32x4 st = mfma16(kf[mf], qf[nf], (f32x4){0.f, 0.f, 0.f, 0.f});
                float p0 = 1.f + st[0] * (1.f + 0.5f * st[0]);
                float p1 = 1.f + st[1] * (1.f + 0.5f * st[1]);
                float p2 = 1.f + st[2] * (1.f + 0.5f * st[2]);
                float p3 = 1.f + st[3] * (1.f + 0.5f * st[3]);
                den[nf] += (p0 + p1) + (p2 + p3);
                asm("v_cvt_pk_bf16_f32 %0, %1, %2" : "=v"(c01[mf]) : "v"(p0), "v"(p1));
                asm("v_cvt_pk_bf16_f32 %0, %1, %2" : "=v"(c23[mf]) : "v"(p2), "v"(p3));
            }
#pragma unroll
            for (int kb = 0; kb < 2; ++kb) {
                u32x2 x0 = __builtin_amdgcn_permlane32_swap(c01[2 * kb], c01[2 * kb + 1], 0, 0);
                u32x2 w02 = __builtin_amdgcn_permlane16_swap(x0.x, x0.y, 0, 0);
                u32x2 x1 = __builtin_amdgcn_permlane32_swap(c23[2 * kb], c23[2 * kb + 1], 0, 0);
                u32x2 w13 = __builtin_amdgcn_permlane16_swap(x1.x, x1.y, 0, 0);
                uint4 u = {w02.x, w13.x, w02.y, w13.y};
                bf16x8 pf = *(bf16x8*)&u;
#pragma unroll
                for (int df = 0; df < 4; ++df)
                    accn[nf][df] = mfma16(pf, vf[kb][df], accn[nf][df]);
            }
        }
        __syncthreads();                            // barrier 2
    }

    float invq[2][4];
#pragma unroll
    for (int nf = 0; nf < 2; ++nf) {
        float d = den[nf];
        d += __shfl_xor(d, 16, 64);
        d += __shfl_xor(d, 32, 64);
#pragma unroll
        for (int q = 0; q < 4; ++q)
            invq[nf][q] = 0.5f / (__shfl(d, (lane & 48) + lk * 4 + q, 64) + 1e-6f);
    }

    if (s == 0) {
#pragma unroll
        for (int nf = 0; nf < 2; ++nf)
#pragma unroll
            for (int q = 0; q < 4; ++q)
#pragma unroll
                for (int df = 0; df < 4; ++df)
                    OS(hq * 32 + nf * 16 + lk * 4 + q, df * 16 + l16) =
                        accn[nf][df][q] * invq[nf][q];
    }
    __syncthreads();
    if (s == 1) {
        const int b = bh >> 4, h = bh & 15;
#pragma unroll
        for (int nf = 0; nf < 2; ++nf)
#pragma unroll
            for (int q = 0; q < 4; ++q) {
                const int n = hq * 32 + nf * 16 + lk * 4 + q;
#pragma unroll
                for (int df = 0; df < 4; ++df) {
                    const int d = df * 16 + l16;
                    float o = OS(n, d) + accn[nf][df][q] * invq[nf][q];
                    size_t addr = ((size_t)b * NN + n0 + n) * CC + h * 64 + d;
                    short hi = f2bf(o);
                    aoh[addr] = hi;
                    aol[addr] = f2bf(o - bf2f(hi));
                }
            }
    }
#undef KS
#undef VT
#undef OS
}

// ---------------------------------------------------------------------------
// Output projection, 3-term split-bf16, BK=32 (champion). 256 thr / 4 waves.
// flat grid 512; logical = row*16 + col (XCD-chunked).
// ---------------------------------------------------------------------------
__global__ __launch_bounds__(256) void wo_proj(
    const short* __restrict__ aoh, const short* __restrict__ aol,
    const float* __restrict__ Wo, const float* __restrict__ bo,
    float* __restrict__ outp)
{
    __shared__ short Ah[64][40], Al[64][40], Wh[64][40], Wl[64][40];

    const int L = xcd_logical(blockIdx.x, 512);
    const int row0 = (L >> 4) * 64;
    const int col0 = (L & 15) * 64;

    const int tid  = threadIdx.x;
    const int lane = tid & 63, wave = tid >> 6;
    const int wr = wave >> 1, wc = wave & 1;
    const int l16 = lane & 15, lk = lane >> 4;

    const int ar  = tid >> 2, ac8 = (tid & 3) << 3;
    const int wrr = tid >> 3, wc4 = (tid & 7) << 2;

    uint4 ph, pl;
    float4 pw[2];
    ph = *(const uint4*)&aoh[(size_t)(row0 + ar) * CC + ac8];
    pl = *(const uint4*)&aol[(size_t)(row0 + ar) * CC + ac8];
#pragma unroll
    for (int p = 0; p < 2; ++p)
        pw[p] = *(const float4*)&Wo[(size_t)(col0 + p * 32 + wrr) * CC + wc4];

    f32x4 acc[2][2];
#pragma unroll
    for (int i = 0; i < 2; ++i)
#pragma unroll
        for (int j = 0; j < 2; ++j) acc[i][j] = (f32x4){0.f, 0.f, 0.f, 0.f};

    for (int k0 = 0; k0 < CC; k0 += 32) {
        *(uint4*)&Ah[ar][ac8] = ph;
        *(uint4*)&Al[ar][ac8] = pl;
#pragma unroll
        for (int p = 0; p < 2; ++p) {
            float v[4] = {pw[p].x, pw[p].y, pw[p].z, pw[p].w};
            unsigned short hs[4], ls[4];
#pragma unroll
            for (int j = 0; j < 4; ++j) {
                short hv = f2bf(v[j]);
                hs[j] = (unsigned short)hv;
                ls[j] = (unsigned short)f2bf(v[j] - bf2f(hv));
            }
            *(ushort4*)&Wh[p * 32 + wrr][wc4] = (ushort4){hs[0], hs[1], hs[2], hs[3]};
            *(ushort4*)&Wl[p * 32 + wrr][wc4] = (ushort4){ls[0], ls[1], ls[2], ls[3]};
        }
        if (k0 + 32 < CC) {
            ph = *(const uint4*)&aoh[(size_t)(row0 + ar) * CC + k0 + 32 + ac8];
            pl = *(const uint4*)&aol[(size_t)(row0 + ar) * CC + k0 + 32 + ac8];
#pragma unroll
            for (int p = 0; p < 2; ++p)
                pw[p] = *(const float4*)&Wo[(size_t)(col0 + p * 32 + wrr) * CC + k0 + 32 + wc4];
        }
        __syncthreads();
        bf16x8 ah[2], al[2], wh[2], wl[2];
#pragma unroll
        for (int i = 0; i < 2; ++i) {
            ah[i] = *(const bf16x8*)&Ah[wr * 32 + i * 16 + l16][lk * 8];
            al[i] = *(const bf16x8*)&Al[wr * 32 + i * 16 + l16][lk * 8];
            wh[i] = *(const bf16x8*)&Wh[wc * 32 + i * 16 + l16][lk * 8];
            wl[i] = *(const bf16x8*)&Wl[wc * 32 + i * 16 + l16][lk * 8];
        }
#pragma unroll
        for (int mi = 0; mi < 2; ++mi)
#pragma unroll
            for (int nj = 0; nj < 2; ++nj) {
                acc[mi][nj] = mfma16(ah[mi], wh[nj], acc[mi][nj]);
                acc[mi][nj] = mfma16(ah[mi], wl[nj], acc[mi][nj]);
                acc[mi][nj] = mfma16(al[mi], wh[nj], acc[mi][nj]);
            }
        __syncthreads();
    }

#pragma unroll
    for (int mi = 0; mi < 2; ++mi)
#pragma unroll
        for (int q = 0; q < 4; ++q) {
            const int r = row0 + wr * 32 + mi * 16 + lk * 4 + q;
#pragma unroll
            for (int nj = 0; nj < 2; ++nj) {
                const int o = col0 + wc * 32 + nj * 16 + l16;
                outp[(size_t)r * CC + o] = acc[mi][nj][q] + bo[o];
            }
        }
}

extern "C" void kernel_launch(void* const* d_in, const int* in_sizes, int n_in,
                              void* d_out, int out_size, void* d_ws, size_t ws_size,
                              hipStream_t stream) {
    const float* query = (const float*)d_in[0];
    const float* key_  = (const float*)d_in[1];
    const float* value = (const float*)d_in[2];
    const float* Wq = (const float*)d_in[3];
    const float* bq = (const float*)d_in[4];
    const float* Wk = (const float*)d_in[5];
    const float* bk = (const float*)d_in[6];
    const float* Wv = (const float*)d_in[7];
    const float* bv = (const float*)d_in[8];
    const float* Wo = (const float*)d_in[9];
    const float* bo = (const float*)d_in[10];
    float* out = (float*)d_out;

    short* qt  = (short*)d_ws;                 // 4 MB  [b][h][s][n][32]
    short* kt  = qt  + ((size_t)1 << 21);      // 4 MB  [b][h][s][m][32]
    short* vt  = kt  + ((size_t)1 << 21);      // 4 MB  [b][h][d][m]
    short* aoh = vt  + ((size_t)1 << 21);      // 4 MB  attn out hi
    short* aol = aoh + ((size_t)1 << 21);      // 4 MB  attn out lo

    qkv_proj<<<dim3(768), dim3(512), 0, stream>>>(query, key_, value, Wq, Wk, Wv,
                                                  bq, bk, bv, qt, kt, vt);
    attn_mfma<<<dim3(256), dim3(512), 0, stream>>>(qt, kt, vt, aoh, aol);
    wo_proj<<<dim3(512), dim3(256), 0, stream>>>(aoh, aol, Wo, bo, out);
}

// Round 35
// 78.090 us; speedup vs baseline: 1.0032x; 1.0008x over previous
//
#include <hip/hip_runtime.h>
#include <hip/hip_bf16.h>

#define CC 1024
#define NN 1024
#define BB 2
#define HH 16
#define NT (NN / 64)
#define QSCALE 0.17677669529663687f  // 1/sqrt(32)

typedef short bf16x8 __attribute__((ext_vector_type(8)));
typedef float f32x4  __attribute__((ext_vector_type(4)));
typedef unsigned int u32x2 __attribute__((ext_vector_type(2)));

__device__ __forceinline__ f32x4 mfma16(bf16x8 a, bf16x8 b, f32x4 c) {
    return __builtin_amdgcn_mfma_f32_16x16x32_bf16(a, b, c, 0, 0, 0);
}
__device__ __forceinline__ short f2bf(float x) {
    __hip_bfloat16 h = __float2bfloat16(x);
    return *reinterpret_cast<short*>(&h);
}
__device__ __forceinline__ float bf2f(short s) {
    __hip_bfloat16 h;
    *reinterpret_cast<short*>(&h) = s;
    return __bfloat162float(h);
}
// XCD-chunked swizzle (bijective when nwg % 8 == 0).
__device__ __forceinline__ int xcd_logical(int hw, int nwg) {
    return (hw & 7) * (nwg >> 3) + (hw >> 3);
}

// ---------------------------------------------------------------------------
// Fused QKV projection (champion): tile 128x64, BK=64, 512 thr / 8 waves,
// per-wave 32x32, grid 768 (XCD-chunked), 6 waves/SIMD.
// ---------------------------------------------------------------------------
__global__ __launch_bounds__(512) void qkv_proj(
    const float* __restrict__ xq, const float* __restrict__ xk, const float* __restrict__ xv,
    const float* __restrict__ wq, const float* __restrict__ wk, const float* __restrict__ wv,
    const float* __restrict__ bq, const float* __restrict__ bk, const float* __restrict__ bv,
    short* __restrict__ qt, short* __restrict__ kt, short* __restrict__ vt)
{
    __shared__ short LD[13824];                        // 27,648 B
    short (*A)[72]  = (short(*)[72])LD;                // 128 x 72
    short (*Bt)[72] = (short(*)[72])(LD + 128 * 72);   // 64 x 72
    short (*T)[136] = (short(*)[136])LD;               // z=2 overlay: 64 x 136

    const int L = xcd_logical(blockIdx.x, 768);
    const int z = L >> 8;                 // /256
    const int rem = L & 255;
    const int row0 = (rem >> 4) * 128;    // 16 row-blocks
    const int col0 = (rem & 15) * 64;     // 16 col-blocks

    const int tid  = threadIdx.x;
    const int lane = tid & 63, wid = tid >> 6;     // 8 waves
    const int wr = wid >> 1, wc = wid & 1;         // 4 x 2: per-wave 32 x 32
    const int l16 = lane & 15, lk = lane >> 4;

    const float* X    = (z == 0) ? xq : (z == 1) ? xk : xv;
    const float* W    = (z == 0) ? wq : (z == 1) ? wk : wv;
    const float* bias = (z == 0) ? bq : (z == 1) ? bk : bv;

    const int str = tid >> 4;          // 0..31
    const int stc = (tid & 15) << 2;   // 0..60

    float4 pa[4], pb[2];
#pragma unroll
    for (int p = 0; p < 4; ++p)
        pa[p] = *(const float4*)&X[(size_t)(row0 + p * 32 + str) * CC + stc];
#pragma unroll
    for (int p = 0; p < 2; ++p)
        pb[p] = *(const float4*)&W[(size_t)(col0 + p * 32 + str) * CC + stc];

    f32x4 acc[2][2];
#pragma unroll
    for (int i = 0; i < 2; ++i)
#pragma unroll
        for (int j = 0; j < 2; ++j) acc[i][j] = (f32x4){0.f, 0.f, 0.f, 0.f};

    for (int k0 = 0; k0 < CC; k0 += 64) {
#pragma unroll
        for (int p = 0; p < 4; ++p) {
            ushort4 ua = { (unsigned short)f2bf(pa[p].x), (unsigned short)f2bf(pa[p].y),
                           (unsigned short)f2bf(pa[p].z), (unsigned short)f2bf(pa[p].w) };
            *(ushort4*)&A[p * 32 + str][stc] = ua;
        }
#pragma unroll
        for (int p = 0; p < 2; ++p) {
            ushort4 ub = { (unsigned short)f2bf(pb[p].x), (unsigned short)f2bf(pb[p].y),
                           (unsigned short)f2bf(pb[p].z), (unsigned short)f2bf(pb[p].w) };
            *(ushort4*)&Bt[p * 32 + str][stc] = ub;
        }
        if (k0 + 64 < CC) {
#pragma unroll
            for (int p = 0; p < 4; ++p)
                pa[p] = *(const float4*)&X[(size_t)(row0 + p * 32 + str) * CC + k0 + 64 + stc];
#pragma unroll
            for (int p = 0; p < 2; ++p)
                pb[p] = *(const float4*)&W[(size_t)(col0 + p * 32 + str) * CC + k0 + 64 + stc];
        }
        __syncthreads();
#pragma unroll
        for (int ks = 0; ks < 2; ++ks) {
            bf16x8 af[2], bw[2];
#pragma unroll
            for (int i = 0; i < 2; ++i)
                af[i] = *(const bf16x8*)&A[wr * 32 + i * 16 + l16][ks * 32 + lk * 8];
#pragma unroll
            for (int j = 0; j < 2; ++j)
                bw[j] = *(const bf16x8*)&Bt[wc * 32 + j * 16 + l16][ks * 32 + lk * 8];
#pragma unroll
            for (int mi = 0; mi < 2; ++mi)
#pragma unroll
                for (int nf = 0; nf < 2; ++nf)
                    acc[mi][nf] = mfma16(af[mi], bw[nf], acc[mi][nf]);
        }
        __syncthreads();
    }

    if (z <= 1) {
        short* outp = (z == 0) ? qt : kt;
        const float scl = (z == 0) ? QSCALE : 1.f;
#pragma unroll
        for (int mi = 0; mi < 2; ++mi)
#pragma unroll
            for (int q = 0; q < 4; ++q) {
                const int r = row0 + wr * 32 + mi * 16 + lk * 4 + q;
                const int b = r >> 10, n = r & 1023;
#pragma unroll
                for (int nf = 0; nf < 2; ++nf) {
                    const int o = col0 + wc * 32 + nf * 16 + l16;
                    const int h = o >> 6, s = (o >> 5) & 1, ii = o & 31;
                    float y = (acc[mi][nf][q] + bias[o]) * scl;
                    outp[(((size_t)((b * HH + h) * 2 + s)) << 15) + n * 32 + ii] = f2bf(y);
                }
            }
    } else {
        // transpose through LDS: T[col-in-block 0..63][row-in-block 0..127]
#pragma unroll
        for (int mi = 0; mi < 2; ++mi)
#pragma unroll
            for (int nf = 0; nf < 2; ++nf)
#pragma unroll
                for (int q = 0; q < 4; ++q) {
                    const int c = wc * 32 + nf * 16 + l16;
                    const int r = wr * 32 + mi * 16 + lk * 4 + q;
                    T[c][r] = f2bf(acc[mi][nf][q] + bias[col0 + c]);
                }
        __syncthreads();
        const int b  = row0 >> 10, n0 = row0 & 1023;
        const int c  = tid >> 3, seg = tid & 7;    // 8 threads/col, 16 rows each
        const int oc = col0 + c, h = oc >> 6, d = oc & 63;
        const size_t base = (((size_t)(b * HH + h)) * 64 + d) * NN + n0 + seg * 16;
#pragma unroll
        for (int u = 0; u < 2; ++u)
            *(uint4*)&vt[base + u * 8] = *(const uint4*)&T[c][seg * 16 + u * 8];
    }
}

// ---------------------------------------------------------------------------
// Attention core (champion). flat grid 256; 512 thr / 8 waves.
// ---------------------------------------------------------------------------
__global__ __launch_bounds__(512) void attn_mfma(
    const short* __restrict__ qt, const short* __restrict__ kt,
    const short* __restrict__ vtg, short* __restrict__ aoh, short* __restrict__ aol)
{
    __shared__ __align__(16) short LDS_[17408];           // 34,816 B
    short* KsB = LDS_;                                    // [2 sig][64][40]
    short* VtB = LDS_ + 5120;                             // [64][72]
    float* OsB = (float*)LDS_;                            // [128][68] epilogue overlay

#define KS(ss, r, c)  KsB[((ss) * 64 + (r)) * 40 + (c)]
#define VT(d, m)      VtB[(d) * 72 + (m)]
#define OS(n, d)      OsB[(n) * 68 + (d)]

    const int L = xcd_logical(blockIdx.x, 256);
    const int bh = L >> 3;
    const int n0 = (L & 7) * 128;

    const int tid  = threadIdx.x;
    const int lane = tid & 63;
    const int wid  = tid >> 6;
    const int s  = wid >> 2;
    const int hq = wid & 3;
    const int l16 = lane & 15, lk = lane >> 4;

    bf16x8 qf[2];
#pragma unroll
    for (int nf = 0; nf < 2; ++nf)
        qf[nf] = *(const bf16x8*)&qt[((size_t)(bh * 2 + s) * NN + n0 + hq * 32 + nf * 16 + l16) * 32 + lk * 8];

    const int kss = tid >> 8, kj = tid & 255, kr = kj >> 2, kc8 = (kj & 3) << 3;
    const int vd = tid >> 3, vc8 = (tid & 7) << 3;

    uint4 kpf, vpf;
    auto load_tiles = [&](int m0) {
        kpf = *(const uint4*)&kt[((size_t)(bh * 2 + kss) * NN + m0 + kr) * 32 + kc8];
        vpf = *(const uint4*)&vtg[((size_t)(bh * 64 + vd)) * NN + m0 + vc8];
    };
    auto commit_tiles = [&]() {
        *(uint4*)&KS(kss, kr, kc8) = kpf;
        *(uint4*)&VT(vd, vc8) = vpf;
    };

    f32x4 accn[2][4];
#pragma unroll
    for (int nf = 0; nf < 2; ++nf)
#pragma unroll
        for (int df = 0; df < 4; ++df) accn[nf][df] = (f32x4){0.f, 0.f, 0.f, 0.f};
    float den[2] = {0.f, 0.f};

    load_tiles(0);

    for (int t = 0; t < NT; ++t) {
        commit_tiles();
        if (t + 1 < NT) load_tiles((t + 1) * 64);
        __syncthreads();                            // barrier 1

        bf16x8 kf[4], vf[2][4];
#pragma unroll
        for (int mf = 0; mf < 4; ++mf)
            kf[mf] = *(const bf16x8*)&KS(s, mf * 16 + l16, lk * 8);
#pragma unroll
        for (int kb = 0; kb < 2; ++kb)
#pragma unroll
            for (int df = 0; df < 4; ++df)
                vf[kb][df] = *(const bf16x8*)&VT(df * 16 + l16, kb * 32 + lk * 8);

#pragma unroll
        for (int nf = 0; nf < 2; ++nf) {
            unsigned c01[4], c23[4];
#pragma unroll
            for (int mf = 0; mf < 4; ++mf) {
                f32x4 st = mfma16(kf[mf], qf[nf], (f32x4){0.f, 0.f, 0.f, 0.f});
                float p0 = 1.f + st[0] * (1.f + 0.5f * st[0]);
                float p1 = 1.f + st[1] * (1.f + 0.5f * st[1]);
                float p2 = 1.f + st[2] * (1.f + 0.5f * st[2]);
                float p3 = 1.f + st[3] * (1.f + 0.5f * st[3]);
                den[nf] += (p0 + p1) + (p2 + p3);
                asm("v_cvt_pk_bf16_f32 %0, %1, %2" : "=v"(c01[mf]) : "v"(p0), "v"(p1));
                asm("v_cvt_pk_bf16_f32 %0, %1, %2" : "=v"(c23[mf]) : "v"(p2), "v"(p3));
            }
#pragma unroll
            for (int kb = 0; kb < 2; ++kb) {
                u32x2 x0 = __builtin_amdgcn_permlane32_swap(c01[2 * kb], c01[2 * kb + 1], 0, 0);
                u32x2 w02 = __builtin_amdgcn_permlane16_swap(x0.x, x0.y, 0, 0);
                u32x2 x1 = __builtin_amdgcn_permlane32_swap(c23[2 * kb], c23[2 * kb + 1], 0, 0);
                u32x2 w13 = __builtin_amdgcn_permlane16_swap(x1.x, x1.y, 0, 0);
                uint4 u = {w02.x, w13.x, w02.y, w13.y};
                bf16x8 pf = *(bf16x8*)&u;
#pragma unroll
                for (int df = 0; df < 4; ++df)
                    accn[nf][df] = mfma16(pf, vf[kb][df], accn[nf][df]);
            }
        }
        __syncthreads();                            // barrier 2
    }

    float invq[2][4];
#pragma unroll
    for (int nf = 0; nf < 2; ++nf) {
        float d = den[nf];
        d += __shfl_xor(d, 16, 64);
        d += __shfl_xor(d, 32, 64);
#pragma unroll
        for (int q = 0; q < 4; ++q)
            invq[nf][q] = 0.5f / (__shfl(d, (lane & 48) + lk * 4 + q, 64) + 1e-6f);
    }

    if (s == 0) {
#pragma unroll
        for (int nf = 0; nf < 2; ++nf)
#pragma unroll
            for (int q = 0; q < 4; ++q)
#pragma unroll
                for (int df = 0; df < 4; ++df)
                    OS(hq * 32 + nf * 16 + lk * 4 + q, df * 16 + l16) =
                        accn[nf][df][q] * invq[nf][q];
    }
    __syncthreads();
    if (s == 1) {
        const int b = bh >> 4, h = bh & 15;
#pragma unroll
        for (int nf = 0; nf < 2; ++nf)
#pragma unroll
            for (int q = 0; q < 4; ++q) {
                const int n = hq * 32 + nf * 16 + lk * 4 + q;
#pragma unroll
                for (int df = 0; df < 4; ++df) {
                    const int d = df * 16 + l16;
                    float o = OS(n, d) + accn[nf][df][q] * invq[nf][q];
                    size_t addr = ((size_t)b * NN + n0 + n) * CC + h * 64 + d;
                    short hi = f2bf(o);
                    aoh[addr] = hi;
                    aol[addr] = f2bf(o - bf2f(hi));
                }
            }
    }
#undef KS
#undef VT
#undef OS
}

// ---------------------------------------------------------------------------
// Output projection, 3-term split-bf16, BK=32 (champion). 256 thr / 4 waves.
// flat grid 512; logical = row*16 + col (XCD-chunked).
// ---------------------------------------------------------------------------
__global__ __launch_bounds__(256) void wo_proj(
    const short* __restrict__ aoh, const short* __restrict__ aol,
    const float* __restrict__ Wo, const float* __restrict__ bo,
    float* __restrict__ outp)
{
    __shared__ short Ah[64][40], Al[64][40], Wh[64][40], Wl[64][40];

    const int L = xcd_logical(blockIdx.x, 512);
    const int row0 = (L >> 4) * 64;
    const int col0 = (L & 15) * 64;

    const int tid  = threadIdx.x;
    const int lane = tid & 63, wave = tid >> 6;
    const int wr = wave >> 1, wc = wave & 1;
    const int l16 = lane & 15, lk = lane >> 4;

    const int ar  = tid >> 2, ac8 = (tid & 3) << 3;
    const int wrr = tid >> 3, wc4 = (tid & 7) << 2;

    uint4 ph, pl;
    float4 pw[2];
    ph = *(const uint4*)&aoh[(size_t)(row0 + ar) * CC + ac8];
    pl = *(const uint4*)&aol[(size_t)(row0 + ar) * CC + ac8];
#pragma unroll
    for (int p = 0; p < 2; ++p)
        pw[p] = *(const float4*)&Wo[(size_t)(col0 + p * 32 + wrr) * CC + wc4];

    f32x4 acc[2][2];
#pragma unroll
    for (int i = 0; i < 2; ++i)
#pragma unroll
        for (int j = 0; j < 2; ++j) acc[i][j] = (f32x4){0.f, 0.f, 0.f, 0.f};

    for (int k0 = 0; k0 < CC; k0 += 32) {
        *(uint4*)&Ah[ar][ac8] = ph;
        *(uint4*)&Al[ar][ac8] = pl;
#pragma unroll
        for (int p = 0; p < 2; ++p) {
            float v[4] = {pw[p].x, pw[p].y, pw[p].z, pw[p].w};
            unsigned short hs[4], ls[4];
#pragma unroll
            for (int j = 0; j < 4; ++j) {
                short hv = f2bf(v[j]);
                hs[j] = (unsigned short)hv;
                ls[j] = (unsigned short)f2bf(v[j] - bf2f(hv));
            }
            *(ushort4*)&Wh[p * 32 + wrr][wc4] = (ushort4){hs[0], hs[1], hs[2], hs[3]};
            *(ushort4*)&Wl[p * 32 + wrr][wc4] = (ushort4){ls[0], ls[1], ls[2], ls[3]};
        }
        if (k0 + 32 < CC) {
            ph = *(const uint4*)&aoh[(size_t)(row0 + ar) * CC + k0 + 32 + ac8];
            pl = *(const uint4*)&aol[(size_t)(row0 + ar) * CC + k0 + 32 + ac8];
#pragma unroll
            for (int p = 0; p < 2; ++p)
                pw[p] = *(const float4*)&Wo[(size_t)(col0 + p * 32 + wrr) * CC + k0 + 32 + wc4];
        }
        __syncthreads();
        bf16x8 ah[2], al[2], wh[2], wl[2];
#pragma unroll
        for (int i = 0; i < 2; ++i) {
            ah[i] = *(const bf16x8*)&Ah[wr * 32 + i * 16 + l16][lk * 8];
            al[i] = *(const bf16x8*)&Al[wr * 32 + i * 16 + l16][lk * 8];
            wh[i] = *(const bf16x8*)&Wh[wc * 32 + i * 16 + l16][lk * 8];
            wl[i] = *(const bf16x8*)&Wl[wc * 32 + i * 16 + l16][lk * 8];
        }
#pragma unroll
        for (int mi = 0; mi < 2; ++mi)
#pragma unroll
            for (int nj = 0; nj < 2; ++nj) {
                acc[mi][nj] = mfma16(ah[mi], wh[nj], acc[mi][nj]);
                acc[mi][nj] = mfma16(ah[mi], wl[nj], acc[mi][nj]);
                acc[mi][nj] = mfma16(al[mi], wh[nj], acc[mi][nj]);
            }
        __syncthreads();
    }

#pragma unroll
    for (int mi = 0; mi < 2; ++mi)
#pragma unroll
        for (int q = 0; q < 4; ++q) {
            const int r = row0 + wr * 32 + mi * 16 + lk * 4 + q;
#pragma unroll
            for (int nj = 0; nj < 2; ++nj) {
                const int o = col0 + wc * 32 + nj * 16 + l16;
                outp[(size_t)r * CC + o] = acc[mi][nj][q] + bo[o];
            }
        }
}

extern "C" void kernel_launch(void* const* d_in, const int* in_sizes, int n_in,
                              void* d_out, int out_size, void* d_ws, size_t ws_size,
                              hipStream_t stream) {
    const float* query = (const float*)d_in[0];
    const float* key_  = (const float*)d_in[1];
    const float* value = (const float*)d_in[2];
    const float* Wq = (const float*)d_in[3];
    const float* bq = (const float*)d_in[4];
    const float* Wk = (const float*)d_in[5];
    const float* bk = (const float*)d_in[6];
    const float* Wv = (const float*)d_in[7];
    const float* bv = (const float*)d_in[8];
    const float* Wo = (const float*)d_in[9];
    const float* bo = (const float*)d_in[10];
    float* out = (float*)d_out;

    short* qt  = (short*)d_ws;                 // 4 MB  [b][h][s][n][32]
    short* kt  = qt  + ((size_t)1 << 21);      // 4 MB  [b][h][s][m][32]
    short* vt  = kt  + ((size_t)1 << 21);      // 4 MB  [b][h][d][m]
    short* aoh = vt  + ((size_t)1 << 21);      // 4 MB  attn out hi
    short* aol = aoh + ((size_t)1 << 21);      // 4 MB  attn out lo

    qkv_proj<<<dim3(768), dim3(512), 0, stream>>>(query, key_, value, Wq, Wk, Wv,
                                                  bq, bk, bv, qt, kt, vt);
    attn_mfma<<<dim3(256), dim3(512), 0, stream>>>(qt, kt, vt, aoh, aol);
    wo_proj<<<dim3(512), dim3(256), 0, stream>>>(aoh, aol, Wo, bo, out);
}